// Round 10
// baseline (699.777 us; speedup 1.0000x reference)
//
#include <hip/hip_runtime.h>
#include <math.h>

// Problem constants
#define N_TOK   16384
#define N_E     16384
#define CDIM    256
#define NCH     8
#define CHSZ    (N_E / NCH)      // 2048 codes per chunk
#define L2E100  144.26950408889634f   // 100 * log2(e)
#define DELTA_C 0.06f            // candidate window below running row max (t-units)
#define DELTA_D 0.03f            // same window in dot-units (t = 2*dot)
#define EPS_NT  0.008f           // near-tie window for fp64 argmin re-rank
#define CAP_BLK 1536u            // per-block candidate cap (proven r6-r14)
#define NT_CAP  65536u

typedef __attribute__((ext_vector_type(8))) short short8;
typedef __attribute__((ext_vector_type(4))) float f32x4;

// ---- workspace layout (float offsets); base 42.5 MB, zT optional tail ----
#define OFF_A2   0u          // ushort[16384*256] bf16-hi normalized z (token-major)
#define OFF_B2   2097152u    // ushort[16384*256] bf16-hi normalized emb
#define OFF_RMX  4194304u    // 16384 u32 ordered-key row max
#define OFF_CS   4210688u    // 16384 colsum
#define OFF_SC   4227072u    // 16 scalars
#define OFF_RK   4227088u    // 16384 u64 rowkey (8B aligned)
#define OFF_NT   4259856u    // 65536 u32 near-tie list
#define OFF_NTC  4325392u    // 16
#define OFF_CBC  4325408u    // 2048 per-block counts
#define OFF_IDX  4327456u    // 16384 int
#define OFF_CAND 4343840u    // u64[2048*1536] {f32 t | row<<14|col} (8B aligned)
#define OFF_ZT   10635296u   // float[16384*256] raw z token-major (refine coalescing)
#define NEED_ZT_BYTES 59318400ull

__device__ __forceinline__ unsigned short f2bf(float x) {
  unsigned u = __float_as_uint(x);
  unsigned r = (u + 0x7fffu + ((u >> 16) & 1u)) >> 16;
  return (unsigned short)r;
}
__device__ __forceinline__ float bf2f(unsigned short h) {
  return __uint_as_float(((unsigned)h) << 16);
}
__device__ __forceinline__ unsigned fkey(float f) {      // order-preserving float->uint
  unsigned u = __float_as_uint(f);
  return (u & 0x80000000u) ? ~u : (u | 0x80000000u);
}
__device__ __forceinline__ float keyf(unsigned k) {
  return (k & 0x80000000u) ? __uint_as_float(k ^ 0x80000000u) : __uint_as_float(~k);
}

__device__ __forceinline__ void async_load16(const void* g, void* l) {
  __builtin_amdgcn_global_load_lds((const __attribute__((address_space(1))) void*)g,
                                   (__attribute__((address_space(3))) void*)l, 16, 0, 0);
}

__device__ __forceinline__ float blockReduceSum256(float v, float* sbuf) {
  __syncthreads();
  v += __shfl_down(v, 32);
  v += __shfl_down(v, 16);
  v += __shfl_down(v, 8);
  v += __shfl_down(v, 4);
  v += __shfl_down(v, 2);
  v += __shfl_down(v, 1);
  const int tid = threadIdx.x;
  if ((tid & 63) == 0) sbuf[tid >> 6] = v;
  __syncthreads();
  return sbuf[0] + sbuf[1] + sbuf[2] + sbuf[3];
}

// ---------- emb normalize (wave-per-row) + fused workspace zeroing ----------
__global__ __launch_bounds__(256) void k_norm_emb(const float* __restrict__ emb,
    unsigned short* __restrict__ B2, float* __restrict__ colsum,
    float* __restrict__ scalars, unsigned long long* __restrict__ rowkey,
    unsigned* __restrict__ ntc, unsigned* __restrict__ rowMaxU) {
  const int tid = threadIdx.x, lane = tid & 63, wv = tid >> 6;
  if (blockIdx.x < 64) {
    const int i = blockIdx.x * 256 + tid;
    colsum[i] = 0.f;
    rowkey[i] = ~0ull;
    rowMaxU[i] = 0u;
    if (i < 16) { scalars[i] = 0.f; ntc[i] = 0u; }
  }
  const int k = blockIdx.x * 4 + wv;
  const float4 v = *(const float4*)&emb[(size_t)k * CDIM + lane * 4];
  float ss = v.x * v.x + v.y * v.y + v.z * v.z + v.w * v.w;
#pragma unroll
  for (int off = 1; off < 64; off <<= 1) ss += __shfl_xor(ss, off);
  const float r = 1.0f / fmaxf(sqrtf(ss), 1e-12f);
  ushort4 o;
  o.x = f2bf(v.x * r); o.y = f2bf(v.y * r);
  o.z = f2bf(v.z * r); o.w = f2bf(v.w * r);
  *(ushort4*)&B2[(size_t)k * CDIM + lane * 4] = o;
}

// ---------- coalesced z normalize + optional raw token-major copy ----------
__global__ __launch_bounds__(256) void k_norm_z(const float* __restrict__ z,
                                                unsigned short* __restrict__ A2,
                                                float* __restrict__ zT) {
  __shared__ float ssb[4][64];
  __shared__ float rn[64];
  __shared__ unsigned short tile[64 * 264];
  __shared__ float tileF[64 * 260];
  const int b = blockIdx.x >> 4, hw0 = (blockIdx.x & 15) * 64;
  const int tid = threadIdx.x, cg = tid >> 6, hwl = tid & 63;
  float ss = 0.f;
#pragma unroll 8
  for (int i = 0; i < 64; ++i) {
    const int c = cg + i * 4;
    const float x = z[((size_t)(b * CDIM + c) << 10) + hw0 + hwl];
    ss = fmaf(x, x, ss);
  }
  ssb[cg][hwl] = ss;
  __syncthreads();
  if (tid < 64) {
    const float t = ssb[0][tid] + ssb[1][tid] + ssb[2][tid] + ssb[3][tid];
    rn[tid] = 1.0f / fmaxf(sqrtf(t), 1e-12f);
  }
  __syncthreads();
  const float r = rn[hwl];
#pragma unroll 8
  for (int i = 0; i < 64; ++i) {
    const int c = cg + i * 4;
    const float x = z[((size_t)(b * CDIM + c) << 10) + hw0 + hwl];
    tile[hwl * 264 + c] = f2bf(x * r);
    tileF[hwl * 260 + c] = x;
  }
  __syncthreads();
  const int rr = tid >> 5, tt = tid & 31;
#pragma unroll
  for (int it = 0; it < 8; ++it) {
    const int row = rr + 8 * it;
    const int token = b * 1024 + hw0 + row;
    const uint4 v = *(const uint4*)&tile[row * 264 + tt * 8];
    *(uint4*)&A2[(size_t)token * CDIM + tt * 8] = v;
    if (zT != nullptr) {
      const float4 f0 = *(const float4*)&tileF[row * 260 + tt * 4];
      const float4 f1 = *(const float4*)&tileF[row * 260 + 128 + tt * 4];
      *(float4*)&zT[(size_t)token * CDIM + tt * 4] = f0;
      *(float4*)&zT[(size_t)token * CDIM + 128 + tt * 4] = f1;
    }
  }
}

// ============ pass 1 v3: R7 winner (4 waves, ti=1, wave-local epilogue) with
// 8 x 32-dim K-slice phases and 2 x 8 KB dbuf (was 4 x 64-dim, 2 x 16 KB).
// Same total ds_reads/MFMAs/bytes; LDS 33->16.25 KB so 6+ blocks/CU instead
// of 4 (occupancy 42.5% -> ~75%) — pass1 is latency-bound (R9 evidence).
// Slot perm quad^((row>>1)&3) keeps ds_read_b128 at free 2-way aliasing. ============
__global__ __launch_bounds__(256, 6) void k_pass1(const unsigned short* __restrict__ A2,
    const unsigned short* __restrict__ B2,
    unsigned long long* __restrict__ cand, unsigned* __restrict__ cbc,
    unsigned* __restrict__ rowMaxU) {
  __shared__ alignas(16) unsigned short Bt[2][128 * 32];  // 2 x 8 KB B dbuf
  __shared__ unsigned lcnt;
  const int rt = blockIdx.x, chunk = blockIdx.y;   // swizzle: co-resident blocks share chunk
  const int r0 = rt * 64, k0 = chunk * CHSZ;
  const int blin = rt * NCH + chunk;
  const int tid = threadIdx.x, lane = tid & 63, w = tid >> 6;
  const int wr0 = w * 16;                // wave owns rows wr0..wr0+15, cols 0..127
  const int l15 = lane & 15, quad = lane >> 4;

  if (tid == 0) lcnt = 0u;

  // A fragments -> registers: 8 K-slices of 32 dims (same data as R7's afr[st][kk]).
  short8 afr[8];
  {
    const size_t rbase = (size_t)(r0 + wr0 + l15) * CDIM;
#pragma unroll
    for (int j = 0; j < 8; ++j)
      afr[j] = *(const short8*)&A2[rbase + j * 32 + quad * 8];
  }

  // staging: 2 x 16B per thread per phase. lin = i*256+tid -> row=lin>>2,
  // slot=lin&3; LDS[row][slot] holds global dim-group gcg = slot ^ ((row>>1)&3).
  const unsigned short* bsrc[2];
  unsigned bdst[2];
#pragma unroll
  for (int i = 0; i < 2; ++i) {
    const int lin = i * 256 + tid;
    const int row = lin >> 2, slot = lin & 3;
    const int gcg = slot ^ ((row >> 1) & 3);
    bsrc[i] = B2 + (size_t)(k0 + row) * CDIM + gcg * 8;
    bdst[i] = (unsigned)lin * 16u;
  }

  // read offsets: row br (64B stride), slot quad^((br>>1)&3) -> 2-way max aliasing
  int boff[8];
#pragma unroll
  for (int tj = 0; tj < 8; ++tj) {
    const int br = tj * 16 + l15;
    boff[tj] = br * 32 + ((quad ^ ((br >> 1) & 3)) * 8);
  }

  // prologue: stage phase 0 (ct0, st0) into Bt[0]
#pragma unroll
  for (int i = 0; i < 2; ++i)
    async_load16(bsrc[i], (char*)Bt[0] + bdst[i]);
  __syncthreads();

  f32x4 acc[8];
  float runMax[4];
#pragma unroll
  for (int r = 0; r < 4; ++r) runMax[r] = -3.0e38f;

#pragma unroll 1
  for (int ct = 0; ct < 16; ++ct) {
#pragma unroll
    for (int tj = 0; tj < 8; ++tj) acc[tj] = (f32x4){0.f, 0.f, 0.f, 0.f};

#pragma unroll
    for (int st = 0; st < 8; ++st) {
      // prefetch next 32-dim phase into the other buffer
      if (!(ct == 15 && st == 7)) {
        const int noff = (st < 7) ? (ct * 32768 + (st + 1) * 32)
                                  : ((ct + 1) * 32768);
        char* dbuf = (char*)Bt[(st + 1) & 1];
#pragma unroll
        for (int i = 0; i < 2; ++i)
          async_load16(bsrc[i] + noff, dbuf + bdst[i]);
      }
      const unsigned short* bp = Bt[st & 1];
      short8 bfr[8];
#pragma unroll
      for (int tj = 0; tj < 8; ++tj)
        bfr[tj] = *(const short8*)&bp[boff[tj]];
#pragma unroll
      for (int tj = 0; tj < 8; ++tj)
        acc[tj] = __builtin_amdgcn_mfma_f32_16x16x32_bf16(afr[st], bfr[tj],
                                                          acc[tj], 0, 0, 0);

      if (st == 7) {
        // ---- wave-local epilogue (dot-units; t = 2*dot emitted) ----
        const int kb = k0 + ct * 128;
#pragma unroll
        for (int r = 0; r < 4; ++r) {
          float mt = acc[0][r];
#pragma unroll
          for (int tj = 1; tj < 8; ++tj) mt = fmaxf(mt, acc[tj][r]);
          mt = fmaxf(mt, __shfl_xor(mt, 1));
          mt = fmaxf(mt, __shfl_xor(mt, 2));
          mt = fmaxf(mt, __shfl_xor(mt, 4));
          mt = fmaxf(mt, __shfl_xor(mt, 8));
          runMax[r] = fmaxf(runMax[r], mt);
          const float thrD = runMax[r] - DELTA_D;
          const unsigned rowg = (unsigned)(r0 + wr0 + quad * 4 + r);
#pragma unroll
          for (int tj = 0; tj < 8; ++tj) {
            const float d = acc[tj][r];
            if (d >= thrD) {
              const unsigned slot = atomicAdd(&lcnt, 1u);
              if (slot < CAP_BLK) {
                const float t = d + d;
                const unsigned pr = (rowg << 14) | (unsigned)(kb + tj * 16 + l15);
                cand[(size_t)blin * CAP_BLK + slot] =
                    ((unsigned long long)__float_as_uint(t) << 32) | pr;
              }
            }
          }
        }
      }
      __syncthreads();
    }
  }

  // merge per-wave running row maxima to global (t-units = 2*dot)
#pragma unroll
  for (int r = 0; r < 4; ++r)
    if (l15 == 0)
      atomicMax(&rowMaxU[r0 + wr0 + quad * 4 + r], fkey(runMax[r] + runMax[r]));
  if (tid == 0) cbc[blin] = lcnt < CAP_BLK ? lcnt : CAP_BLK;
}

// ---------- fused candidate processing: block = rt, LDS-local Z/E ----------
__global__ __launch_bounds__(256) void k_cstat2(const unsigned long long* __restrict__ cand,
    const unsigned* __restrict__ cbc, const unsigned* __restrict__ rowMaxU,
    float* __restrict__ colsum, unsigned* __restrict__ ntList,
    unsigned* __restrict__ ntc, float* __restrict__ scalars) {
  __shared__ float lM[64], lZ[64], lE[64], lIZ[64];
  __shared__ float sbuf[4];
  const int rt = blockIdx.x, r0 = rt * 64;
  const int tid = threadIdx.x, lane = tid & 63;
  if (tid < 64) {
    lM[tid] = keyf(rowMaxU[r0 + tid]);
    lZ[tid] = 0.f; lE[tid] = 0.f;
  }
  __syncthreads();
  for (int sub = 0; sub < NCH; ++sub) {
    const int blin = rt * NCH + sub;
    const unsigned cnt = cbc[blin] < CAP_BLK ? cbc[blin] : CAP_BLK;
    for (unsigned i = tid; i < cnt; i += 256u) {
      const unsigned long long e = cand[(size_t)blin * CAP_BLK + i];
      const unsigned pr = (unsigned)(e & 0xFFFFFFFu);
      const float t = __uint_as_float((unsigned)(e >> 32));
      const int rowl = (int)((pr >> 14) & 63u);
      const float d = t - lM[rowl];
      const float ex = exp2f(d * L2E100);
      atomicAdd(&lZ[rowl], ex);
      atomicAdd(&lE[rowl], d * 100.0f * ex);
    }
  }
  __syncthreads();
  float ent = 0.f;
  if (tid < 64) {
    const float Z = lZ[tid];
    lIZ[tid] = 1.0f / Z;
    ent = logf(Z) - lE[tid] / Z;
  }
  const float es = blockReduceSum256(ent, sbuf);
  if (tid == 0) atomicAdd(&scalars[1], es);
  __syncthreads();
  for (int sub = 0; sub < NCH; ++sub) {
    const int blin = rt * NCH + sub;
    const unsigned cnt = cbc[blin] < CAP_BLK ? cbc[blin] : CAP_BLK;
    const unsigned lim = (cnt + 255u) & ~255u;
    for (unsigned i = tid; i < lim; i += 256u) {
      bool nt = false;
      unsigned pr = 0u;
      if (i < cnt) {
        const unsigned long long e = cand[(size_t)blin * CAP_BLK + i];
        pr = (unsigned)(e & 0xFFFFFFFu);
        const float t = __uint_as_float((unsigned)(e >> 32));
        const int rowl = (int)((pr >> 14) & 63u);
        const float d = t - lM[rowl];
        atomicAdd(&colsum[pr & 0x3FFFu], exp2f(d * L2E100) * lIZ[rowl]);
        nt = (d >= -EPS_NT);
      }
      const unsigned long long mask = __ballot(nt);
      const unsigned cw = (unsigned)__popcll(mask);
      unsigned base = 0u;
      if (lane == 0 && cw) base = atomicAdd(ntc, cw);
      base = __shfl((int)base, 0);
      if (nt) {
        const unsigned off = (unsigned)__popcll(mask & ((1ull << lane) - 1ull));
        const unsigned s = base + off;
        if (s < NT_CAP) ntList[s] = pr;
      }
    }
  }
}

// ---------- fp64 re-rank of near-tie candidates (coalesced zT if available) ----------
__global__ __launch_bounds__(256) void k_refine(const float* __restrict__ z,
    const float* __restrict__ zT, const float* __restrict__ emb,
    const unsigned* __restrict__ ntList, const unsigned* __restrict__ ntc,
    unsigned long long* __restrict__ rowkey) {
  const unsigned cnt = *ntc;
  const unsigned lim = cnt < NT_CAP ? cnt : NT_CAP;
  const int lane = threadIdx.x & 63, wv = threadIdx.x >> 6;
  for (unsigned slot = blockIdx.x * 4 + wv; slot < lim; slot += gridDim.x * 4) {
    const unsigned pr = ntList[slot];
    const int n = (int)(pr >> 14), k = (int)(pr & 0x3FFFu);
    const int b = n >> 10, hw = n & 1023;
    double sz = 0.0, se = 0.0, sp = 0.0;
#pragma unroll
    for (int u = 0; u < CDIM / 64; ++u) {
      const int c = lane + u * 64;
      const double zv = (zT != nullptr)
          ? (double)zT[(size_t)n * CDIM + c]
          : (double)z[((size_t)(b * CDIM + c) << 10) + hw];
      const double ev = (double)emb[(size_t)k * CDIM + c];
      sz = fma(zv, zv, sz); se = fma(ev, ev, se); sp = fma(zv, ev, sp);
    }
    for (int off = 32; off; off >>= 1) {
      sz += __shfl_down(sz, off);
      se += __shfl_down(se, off);
      sp += __shfl_down(sp, off);
    }
    if (lane == 0) {
      const double nz = fmax(sqrt(sz), 1e-12);
      const double ne = fmax(sqrt(se), 1e-12);
      const double d = sz / (nz * nz) + se / (ne * ne) - 2.0 * sp / (nz * ne);
      const unsigned long long key =
          (((unsigned long long)(d * 140737488355328.0)) << 14) | (unsigned long long)k;
      atomicMin(&rowkey[n], key);
    }
  }
}

// ---------- z_q gather + idx extraction + vq sums ----------
__global__ __launch_bounds__(256) void k_zq(const unsigned short* __restrict__ A2,
    const unsigned short* __restrict__ B2, const unsigned long long* __restrict__ rowkey,
    const long long* __restrict__ qids, int* __restrict__ idxI,
    float* __restrict__ outIdxF, float* __restrict__ outZ,
    float* __restrict__ scalars) {
  __shared__ int lidx[64];
  __shared__ unsigned short tile[64 * 264];
  __shared__ float sbuf[4];
  const int b = blockIdx.x >> 4, hw0 = (blockIdx.x & 15) * 64;
  const int tid = threadIdx.x;
  if (tid < 64) {
    const int n = b * 1024 + hw0 + tid;
    const unsigned long long key = rowkey[n];
    const int k = (key != ~0ull) ? (int)(key & 0x3FFFull) : 0;
    lidx[tid] = k;
    idxI[n] = k;
    outIdxF[n] = (float)k;
  }
  __syncthreads();
  const long long qid = qids[b];
  const int rr = tid >> 5, tt = tid & 31;
  float vq = 0.f;
#pragma unroll
  for (int it = 0; it < 8; ++it) {
    const int row = rr + 8 * it;
    const int token = b * 1024 + hw0 + row;
    union { uint4 v; unsigned short s[8]; } ev, zv;
    ev.v = *(const uint4*)&B2[(size_t)lidx[row] * CDIM + tt * 8];
    zv.v = *(const uint4*)&A2[(size_t)token * CDIM + tt * 8];
    *(uint4*)&tile[row * 264 + tt * 8] = ev.v;
    float dd = 0.f;
#pragma unroll
    for (int u = 0; u < 8; ++u) {
      const float d = bf2f(ev.s[u]) - bf2f(zv.s[u]);
      dd = fmaf(d, d, dd);
    }
    if ((long long)(row & 31) <= qid) vq += dd;
  }
  const float s = blockReduceSum256(vq, sbuf);
  if (tid == 0) atomicAdd(&scalars[0], s * (1.0f / 256.0f));
  __syncthreads();
  const int cg = tid >> 6, hwl = tid & 63;
#pragma unroll 8
  for (int i = 0; i < 64; ++i) {
    const int c = cg + i * 4;
    outZ[((size_t)(b * CDIM + c) << 10) + hw0 + hwl] = bf2f(tile[hwl * 264 + c]);
  }
}

// ---------- final: avg-entropy from colsum + dead-code + scalar outputs ----------
__global__ __launch_bounds__(256) void k_final(const int* __restrict__ idxI,
    const long long* __restrict__ qids, const float* __restrict__ colsum,
    const float* __restrict__ scalars, float* __restrict__ out) {
  __shared__ float sbuf[4];
  const int tid = threadIdx.x;
  float ae = 0.f;
  for (int i = tid; i < N_E; i += 256) {
    const float q = colsum[i] * (1.0f / (float)N_TOK);
    ae += q * logf(q + 1e-5f);
  }
  const float aes = blockReduceSum256(ae, sbuf);   // = -avg_entropy
  int cnt = 0;
  for (int p = tid; p < 1024; p += 256) {
    const int v = idxI[p];
    bool eq = true;
    for (int b = 1; b < 16; ++b) eq = eq && (idxI[b * 1024 + p] == v);
    cnt += eq ? 1 : 0;
  }
  const float dc = blockReduceSum256((float)cnt, sbuf);
  if (tid == 0) {
    float denom = 0.f;
    for (int b = 0; b < 16; ++b) denom += (float)(qids[b] + 1ll);
    out[4194304] = scalars[0] / denom;
    out[4194305] = 0.25f * scalars[0] / denom;
    out[4194306] = 0.1f * (scalars[1] * (1.0f / (float)N_TOK) + aes);
    out[4194307] = dc * (1.0f / 1024.0f);
  }
}

extern "C" void kernel_launch(void* const* d_in, const int* in_sizes, int n_in,
                              void* d_out, int out_size, void* d_ws, size_t ws_size,
                              hipStream_t stream) {
  const float*      z    = (const float*)d_in[0];
  const float*      emb  = (const float*)d_in[1];
  const long long*  qids = (const long long*)d_in[2];
  float* out = (float*)d_out;
  float* W   = (float*)d_ws;

  unsigned short* A2 = (unsigned short*)(W + OFF_A2);
  unsigned short* B2 = (unsigned short*)(W + OFF_B2);
  unsigned* rowMaxU = (unsigned*)(W + OFF_RMX);
  float* colsum = W + OFF_CS;
  float* scal   = W + OFF_SC;
  unsigned long long* rowkey = (unsigned long long*)(W + OFF_RK);
  unsigned* ntList = (unsigned*)(W + OFF_NT);
  unsigned* ntc    = (unsigned*)(W + OFF_NTC);
  unsigned* cbc    = (unsigned*)(W + OFF_CBC);
  int* idxI        = (int*)(W + OFF_IDX);
  unsigned long long* cand = (unsigned long long*)(W + OFF_CAND);
  float* zT = (ws_size >= NEED_ZT_BYTES) ? (W + OFF_ZT) : (float*)nullptr;

  k_norm_emb<<<dim3(N_E / 4),     dim3(256), 0, stream>>>(emb, B2, colsum, scal,
                                                          rowkey, ntc, rowMaxU);
  k_norm_z  <<<dim3(256),         dim3(256), 0, stream>>>(z, A2, zT);
  k_pass1   <<<dim3(256, NCH),    dim3(256), 0, stream>>>(A2, B2, cand, cbc, rowMaxU);
  k_cstat2  <<<dim3(256),         dim3(256), 0, stream>>>(cand, cbc, rowMaxU, colsum,
                                                          ntList, ntc, scal);
  k_refine  <<<dim3(1024),        dim3(256), 0, stream>>>(z, zT, emb, ntList, ntc, rowkey);
  k_zq      <<<dim3(256),         dim3(256), 0, stream>>>(A2, B2, rowkey, qids,
                                                          idxI, out + 4194308, out, scal);
  k_final   <<<dim3(1),           dim3(256), 0, stream>>>(idxI, qids, colsum, scal, out);
}

// Round 12
// 624.012 us; speedup vs baseline: 1.1214x; 1.1214x over previous
//
#include <hip/hip_runtime.h>
#include <math.h>

// Problem constants
#define N_TOK   16384
#define N_E     16384
#define CDIM    256
#define NCH     8
#define CHSZ    (N_E / NCH)      // 2048 codes per chunk
#define L2E100  144.26950408889634f   // 100 * log2(e)
#define DELTA_C 0.06f            // candidate window below running row max (t-units)
#define DELTA_D 0.03f            // same window in dot-units (t = 2*dot)
#define EPS_NT  0.008f           // near-tie window for fp64 argmin re-rank
#define CAP_BLK 1536u            // per-block candidate cap (proven r6-r14)
#define NT_CAP  65536u

typedef __attribute__((ext_vector_type(8))) short short8;
typedef __attribute__((ext_vector_type(4))) float f32x4;

// ---- workspace layout (float offsets); base 42.5 MB, zT optional tail ----
#define OFF_A2   0u          // ushort[16384*256] bf16-hi normalized z (token-major)
#define OFF_B2   2097152u    // ushort[16384*256] bf16-hi normalized emb
#define OFF_RMX  4194304u    // 16384 u32 ordered-key row max
#define OFF_CS   4210688u    // 16384 colsum
#define OFF_SC   4227072u    // 16 scalars
#define OFF_RK   4227088u    // 16384 u64 rowkey (8B aligned)
#define OFF_NT   4259856u    // 65536 u32 near-tie list
#define OFF_NTC  4325392u    // 16
#define OFF_CBC  4325408u    // 2048 per-block counts
#define OFF_IDX  4327456u    // 16384 int
#define OFF_CAND 4343840u    // u64[2048*1536] {f32 t | row<<14|col} (8B aligned)
#define OFF_ZT   10635296u   // float[16384*256] raw z token-major (refine coalescing)
#define NEED_ZT_BYTES 59318400ull

__device__ __forceinline__ unsigned short f2bf(float x) {
  unsigned u = __float_as_uint(x);
  unsigned r = (u + 0x7fffu + ((u >> 16) & 1u)) >> 16;
  return (unsigned short)r;
}
__device__ __forceinline__ float bf2f(unsigned short h) {
  return __uint_as_float(((unsigned)h) << 16);
}
__device__ __forceinline__ unsigned fkey(float f) {      // order-preserving float->uint
  unsigned u = __float_as_uint(f);
  return (u & 0x80000000u) ? ~u : (u | 0x80000000u);
}
__device__ __forceinline__ float keyf(unsigned k) {
  return (k & 0x80000000u) ? __uint_as_float(k ^ 0x80000000u) : __uint_as_float(~k);
}

__device__ __forceinline__ void async_load16(const void* g, void* l) {
  __builtin_amdgcn_global_load_lds((const __attribute__((address_space(1))) void*)g,
                                   (__attribute__((address_space(3))) void*)l, 16, 0, 0);
}

__device__ __forceinline__ float blockReduceSum256(float v, float* sbuf) {
  __syncthreads();
  v += __shfl_down(v, 32);
  v += __shfl_down(v, 16);
  v += __shfl_down(v, 8);
  v += __shfl_down(v, 4);
  v += __shfl_down(v, 2);
  v += __shfl_down(v, 1);
  const int tid = threadIdx.x;
  if ((tid & 63) == 0) sbuf[tid >> 6] = v;
  __syncthreads();
  return sbuf[0] + sbuf[1] + sbuf[2] + sbuf[3];
}

// ---------- emb normalize (wave-per-row) + fused workspace zeroing ----------
__global__ __launch_bounds__(256) void k_norm_emb(const float* __restrict__ emb,
    unsigned short* __restrict__ B2, float* __restrict__ colsum,
    float* __restrict__ scalars, unsigned long long* __restrict__ rowkey,
    unsigned* __restrict__ ntc, unsigned* __restrict__ rowMaxU) {
  const int tid = threadIdx.x, lane = tid & 63, wv = tid >> 6;
  if (blockIdx.x < 64) {
    const int i = blockIdx.x * 256 + tid;
    colsum[i] = 0.f;
    rowkey[i] = ~0ull;
    rowMaxU[i] = 0u;
    if (i < 16) { scalars[i] = 0.f; ntc[i] = 0u; }
  }
  const int k = blockIdx.x * 4 + wv;
  const float4 v = *(const float4*)&emb[(size_t)k * CDIM + lane * 4];
  float ss = v.x * v.x + v.y * v.y + v.z * v.z + v.w * v.w;
#pragma unroll
  for (int off = 1; off < 64; off <<= 1) ss += __shfl_xor(ss, off);
  const float r = 1.0f / fmaxf(sqrtf(ss), 1e-12f);
  ushort4 o;
  o.x = f2bf(v.x * r); o.y = f2bf(v.y * r);
  o.z = f2bf(v.z * r); o.w = f2bf(v.w * r);
  *(ushort4*)&B2[(size_t)k * CDIM + lane * 4] = o;
}

// ---------- coalesced z normalize + optional raw token-major copy ----------
__global__ __launch_bounds__(256) void k_norm_z(const float* __restrict__ z,
                                                unsigned short* __restrict__ A2,
                                                float* __restrict__ zT) {
  __shared__ float ssb[4][64];
  __shared__ float rn[64];
  __shared__ unsigned short tile[64 * 264];
  __shared__ float tileF[64 * 260];
  const int b = blockIdx.x >> 4, hw0 = (blockIdx.x & 15) * 64;
  const int tid = threadIdx.x, cg = tid >> 6, hwl = tid & 63;
  float ss = 0.f;
#pragma unroll 8
  for (int i = 0; i < 64; ++i) {
    const int c = cg + i * 4;
    const float x = z[((size_t)(b * CDIM + c) << 10) + hw0 + hwl];
    ss = fmaf(x, x, ss);
  }
  ssb[cg][hwl] = ss;
  __syncthreads();
  if (tid < 64) {
    const float t = ssb[0][tid] + ssb[1][tid] + ssb[2][tid] + ssb[3][tid];
    rn[tid] = 1.0f / fmaxf(sqrtf(t), 1e-12f);
  }
  __syncthreads();
  const float r = rn[hwl];
#pragma unroll 8
  for (int i = 0; i < 64; ++i) {
    const int c = cg + i * 4;
    const float x = z[((size_t)(b * CDIM + c) << 10) + hw0 + hwl];
    tile[hwl * 264 + c] = f2bf(x * r);
    tileF[hwl * 260 + c] = x;
  }
  __syncthreads();
  const int rr = tid >> 5, tt = tid & 31;
#pragma unroll
  for (int it = 0; it < 8; ++it) {
    const int row = rr + 8 * it;
    const int token = b * 1024 + hw0 + row;
    const uint4 v = *(const uint4*)&tile[row * 264 + tt * 8];
    *(uint4*)&A2[(size_t)token * CDIM + tt * 8] = v;
    if (zT != nullptr) {
      const float4 f0 = *(const float4*)&tileF[row * 260 + tt * 4];
      const float4 f1 = *(const float4*)&tileF[row * 260 + 128 + tt * 4];
      *(float4*)&zT[(size_t)token * CDIM + tt * 4] = f0;
      *(float4*)&zT[(size_t)token * CDIM + 128 + tt * 4] = f1;
    }
  }
}

// ============ pass 1 v3b: identical to v3 (8 x 32-dim phases, 2 x 8 KB dbuf,
// wave-local epilogue) but launch_bounds(256,5): VGPR cap 102 instead of 85.
// R10's cap-85 spilled acc/afr to scratch (VGPR=40, FETCH 41->169 MB). With
// cap 102 the ~90-reg demand fits; LDS 16.9 KB allows 9 blocks/CU, VGPR
// allows 5 -> 20 waves/CU = 62.5% occupancy (R7: 42.5%). ============
__global__ __launch_bounds__(256, 5) void k_pass1(const unsigned short* __restrict__ A2,
    const unsigned short* __restrict__ B2,
    unsigned long long* __restrict__ cand, unsigned* __restrict__ cbc,
    unsigned* __restrict__ rowMaxU) {
  __shared__ alignas(16) unsigned short Bt[2][128 * 32];  // 2 x 8 KB B dbuf
  __shared__ unsigned lcnt;
  const int rt = blockIdx.x, chunk = blockIdx.y;   // swizzle: co-resident blocks share chunk
  const int r0 = rt * 64, k0 = chunk * CHSZ;
  const int blin = rt * NCH + chunk;
  const int tid = threadIdx.x, lane = tid & 63, w = tid >> 6;
  const int wr0 = w * 16;                // wave owns rows wr0..wr0+15, cols 0..127
  const int l15 = lane & 15, quad = lane >> 4;

  if (tid == 0) lcnt = 0u;

  // A fragments -> registers: 8 K-slices of 32 dims (same data as R7's afr[st][kk]).
  short8 afr[8];
  {
    const size_t rbase = (size_t)(r0 + wr0 + l15) * CDIM;
#pragma unroll
    for (int j = 0; j < 8; ++j)
      afr[j] = *(const short8*)&A2[rbase + j * 32 + quad * 8];
  }

  // staging: 2 x 16B per thread per phase. lin = i*256+tid -> row=lin>>2,
  // slot=lin&3; LDS[row][slot] holds global dim-group gcg = slot ^ ((row>>1)&3).
  const unsigned short* bsrc[2];
  unsigned bdst[2];
#pragma unroll
  for (int i = 0; i < 2; ++i) {
    const int lin = i * 256 + tid;
    const int row = lin >> 2, slot = lin & 3;
    const int gcg = slot ^ ((row >> 1) & 3);
    bsrc[i] = B2 + (size_t)(k0 + row) * CDIM + gcg * 8;
    bdst[i] = (unsigned)lin * 16u;
  }

  // read offsets: row br (64B stride), slot quad^((br>>1)&3) -> 2-way max aliasing
  int boff[8];
#pragma unroll
  for (int tj = 0; tj < 8; ++tj) {
    const int br = tj * 16 + l15;
    boff[tj] = br * 32 + ((quad ^ ((br >> 1) & 3)) * 8);
  }

  // prologue: stage phase 0 (ct0, st0) into Bt[0]
#pragma unroll
  for (int i = 0; i < 2; ++i)
    async_load16(bsrc[i], (char*)Bt[0] + bdst[i]);
  __syncthreads();

  f32x4 acc[8];
  float runMax[4];
#pragma unroll
  for (int r = 0; r < 4; ++r) runMax[r] = -3.0e38f;

#pragma unroll 1
  for (int ct = 0; ct < 16; ++ct) {
#pragma unroll
    for (int tj = 0; tj < 8; ++tj) acc[tj] = (f32x4){0.f, 0.f, 0.f, 0.f};

#pragma unroll
    for (int st = 0; st < 8; ++st) {
      // prefetch next 32-dim phase into the other buffer
      if (!(ct == 15 && st == 7)) {
        const int noff = (st < 7) ? (ct * 32768 + (st + 1) * 32)
                                  : ((ct + 1) * 32768);
        char* dbuf = (char*)Bt[(st + 1) & 1];
#pragma unroll
        for (int i = 0; i < 2; ++i)
          async_load16(bsrc[i] + noff, dbuf + bdst[i]);
      }
      const unsigned short* bp = Bt[st & 1];
      short8 bfr[8];
#pragma unroll
      for (int tj = 0; tj < 8; ++tj)
        bfr[tj] = *(const short8*)&bp[boff[tj]];
#pragma unroll
      for (int tj = 0; tj < 8; ++tj)
        acc[tj] = __builtin_amdgcn_mfma_f32_16x16x32_bf16(afr[st], bfr[tj],
                                                          acc[tj], 0, 0, 0);

      if (st == 7) {
        // ---- wave-local epilogue (dot-units; t = 2*dot emitted) ----
        const int kb = k0 + ct * 128;
#pragma unroll
        for (int r = 0; r < 4; ++r) {
          float mt = acc[0][r];
#pragma unroll
          for (int tj = 1; tj < 8; ++tj) mt = fmaxf(mt, acc[tj][r]);
          mt = fmaxf(mt, __shfl_xor(mt, 1));
          mt = fmaxf(mt, __shfl_xor(mt, 2));
          mt = fmaxf(mt, __shfl_xor(mt, 4));
          mt = fmaxf(mt, __shfl_xor(mt, 8));
          runMax[r] = fmaxf(runMax[r], mt);
          const float thrD = runMax[r] - DELTA_D;
          const unsigned rowg = (unsigned)(r0 + wr0 + quad * 4 + r);
#pragma unroll
          for (int tj = 0; tj < 8; ++tj) {
            const float d = acc[tj][r];
            if (d >= thrD) {
              const unsigned slot = atomicAdd(&lcnt, 1u);
              if (slot < CAP_BLK) {
                const float t = d + d;
                const unsigned pr = (rowg << 14) | (unsigned)(kb + tj * 16 + l15);
                cand[(size_t)blin * CAP_BLK + slot] =
                    ((unsigned long long)__float_as_uint(t) << 32) | pr;
              }
            }
          }
        }
      }
      __syncthreads();
    }
  }

  // merge per-wave running row maxima to global (t-units = 2*dot)
#pragma unroll
  for (int r = 0; r < 4; ++r)
    if (l15 == 0)
      atomicMax(&rowMaxU[r0 + wr0 + quad * 4 + r], fkey(runMax[r] + runMax[r]));
  if (tid == 0) cbc[blin] = lcnt < CAP_BLK ? lcnt : CAP_BLK;
}

// ---------- fused candidate processing: block = rt, LDS-local Z/E ----------
__global__ __launch_bounds__(256) void k_cstat2(const unsigned long long* __restrict__ cand,
    const unsigned* __restrict__ cbc, const unsigned* __restrict__ rowMaxU,
    float* __restrict__ colsum, unsigned* __restrict__ ntList,
    unsigned* __restrict__ ntc, float* __restrict__ scalars) {
  __shared__ float lM[64], lZ[64], lE[64], lIZ[64];
  __shared__ float sbuf[4];
  const int rt = blockIdx.x, r0 = rt * 64;
  const int tid = threadIdx.x, lane = tid & 63;
  if (tid < 64) {
    lM[tid] = keyf(rowMaxU[r0 + tid]);
    lZ[tid] = 0.f; lE[tid] = 0.f;
  }
  __syncthreads();
  for (int sub = 0; sub < NCH; ++sub) {
    const int blin = rt * NCH + sub;
    const unsigned cnt = cbc[blin] < CAP_BLK ? cbc[blin] : CAP_BLK;
    for (unsigned i = tid; i < cnt; i += 256u) {
      const unsigned long long e = cand[(size_t)blin * CAP_BLK + i];
      const unsigned pr = (unsigned)(e & 0xFFFFFFFu);
      const float t = __uint_as_float((unsigned)(e >> 32));
      const int rowl = (int)((pr >> 14) & 63u);
      const float d = t - lM[rowl];
      const float ex = exp2f(d * L2E100);
      atomicAdd(&lZ[rowl], ex);
      atomicAdd(&lE[rowl], d * 100.0f * ex);
    }
  }
  __syncthreads();
  float ent = 0.f;
  if (tid < 64) {
    const float Z = lZ[tid];
    lIZ[tid] = 1.0f / Z;
    ent = logf(Z) - lE[tid] / Z;
  }
  const float es = blockReduceSum256(ent, sbuf);
  if (tid == 0) atomicAdd(&scalars[1], es);
  __syncthreads();
  for (int sub = 0; sub < NCH; ++sub) {
    const int blin = rt * NCH + sub;
    const unsigned cnt = cbc[blin] < CAP_BLK ? cbc[blin] : CAP_BLK;
    const unsigned lim = (cnt + 255u) & ~255u;
    for (unsigned i = tid; i < lim; i += 256u) {
      bool nt = false;
      unsigned pr = 0u;
      if (i < cnt) {
        const unsigned long long e = cand[(size_t)blin * CAP_BLK + i];
        pr = (unsigned)(e & 0xFFFFFFFu);
        const float t = __uint_as_float((unsigned)(e >> 32));
        const int rowl = (int)((pr >> 14) & 63u);
        const float d = t - lM[rowl];
        atomicAdd(&colsum[pr & 0x3FFFu], exp2f(d * L2E100) * lIZ[rowl]);
        nt = (d >= -EPS_NT);
      }
      const unsigned long long mask = __ballot(nt);
      const unsigned cw = (unsigned)__popcll(mask);
      unsigned base = 0u;
      if (lane == 0 && cw) base = atomicAdd(ntc, cw);
      base = __shfl((int)base, 0);
      if (nt) {
        const unsigned off = (unsigned)__popcll(mask & ((1ull << lane) - 1ull));
        const unsigned s = base + off;
        if (s < NT_CAP) ntList[s] = pr;
      }
    }
  }
}

// ---------- fp64 re-rank of near-tie candidates (coalesced zT if available) ----------
__global__ __launch_bounds__(256) void k_refine(const float* __restrict__ z,
    const float* __restrict__ zT, const float* __restrict__ emb,
    const unsigned* __restrict__ ntList, const unsigned* __restrict__ ntc,
    unsigned long long* __restrict__ rowkey) {
  const unsigned cnt = *ntc;
  const unsigned lim = cnt < NT_CAP ? cnt : NT_CAP;
  const int lane = threadIdx.x & 63, wv = threadIdx.x >> 6;
  for (unsigned slot = blockIdx.x * 4 + wv; slot < lim; slot += gridDim.x * 4) {
    const unsigned pr = ntList[slot];
    const int n = (int)(pr >> 14), k = (int)(pr & 0x3FFFu);
    const int b = n >> 10, hw = n & 1023;
    double sz = 0.0, se = 0.0, sp = 0.0;
#pragma unroll
    for (int u = 0; u < CDIM / 64; ++u) {
      const int c = lane + u * 64;
      const double zv = (zT != nullptr)
          ? (double)zT[(size_t)n * CDIM + c]
          : (double)z[((size_t)(b * CDIM + c) << 10) + hw];
      const double ev = (double)emb[(size_t)k * CDIM + c];
      sz = fma(zv, zv, sz); se = fma(ev, ev, se); sp = fma(zv, ev, sp);
    }
    for (int off = 32; off; off >>= 1) {
      sz += __shfl_down(sz, off);
      se += __shfl_down(se, off);
      sp += __shfl_down(sp, off);
    }
    if (lane == 0) {
      const double nz = fmax(sqrt(sz), 1e-12);
      const double ne = fmax(sqrt(se), 1e-12);
      const double d = sz / (nz * nz) + se / (ne * ne) - 2.0 * sp / (nz * ne);
      const unsigned long long key =
          (((unsigned long long)(d * 140737488355328.0)) << 14) | (unsigned long long)k;
      atomicMin(&rowkey[n], key);
    }
  }
}

// ---------- z_q gather + idx extraction + vq sums ----------
__global__ __launch_bounds__(256) void k_zq(const unsigned short* __restrict__ A2,
    const unsigned short* __restrict__ B2, const unsigned long long* __restrict__ rowkey,
    const long long* __restrict__ qids, int* __restrict__ idxI,
    float* __restrict__ outIdxF, float* __restrict__ outZ,
    float* __restrict__ scalars) {
  __shared__ int lidx[64];
  __shared__ unsigned short tile[64 * 264];
  __shared__ float sbuf[4];
  const int b = blockIdx.x >> 4, hw0 = (blockIdx.x & 15) * 64;
  const int tid = threadIdx.x;
  if (tid < 64) {
    const int n = b * 1024 + hw0 + tid;
    const unsigned long long key = rowkey[n];
    const int k = (key != ~0ull) ? (int)(key & 0x3FFFull) : 0;
    lidx[tid] = k;
    idxI[n] = k;
    outIdxF[n] = (float)k;
  }
  __syncthreads();
  const long long qid = qids[b];
  const int rr = tid >> 5, tt = tid & 31;
  float vq = 0.f;
#pragma unroll
  for (int it = 0; it < 8; ++it) {
    const int row = rr + 8 * it;
    const int token = b * 1024 + hw0 + row;
    union { uint4 v; unsigned short s[8]; } ev, zv;
    ev.v = *(const uint4*)&B2[(size_t)lidx[row] * CDIM + tt * 8];
    zv.v = *(const uint4*)&A2[(size_t)token * CDIM + tt * 8];
    *(uint4*)&tile[row * 264 + tt * 8] = ev.v;
    float dd = 0.f;
#pragma unroll
    for (int u = 0; u < 8; ++u) {
      const float d = bf2f(ev.s[u]) - bf2f(zv.s[u]);
      dd = fmaf(d, d, dd);
    }
    if ((long long)(row & 31) <= qid) vq += dd;
  }
  const float s = blockReduceSum256(vq, sbuf);
  if (tid == 0) atomicAdd(&scalars[0], s * (1.0f / 256.0f));
  __syncthreads();
  const int cg = tid >> 6, hwl = tid & 63;
#pragma unroll 8
  for (int i = 0; i < 64; ++i) {
    const int c = cg + i * 4;
    outZ[((size_t)(b * CDIM + c) << 10) + hw0 + hwl] = bf2f(tile[hwl * 264 + c]);
  }
}

// ---------- final: avg-entropy from colsum + dead-code + scalar outputs ----------
__global__ __launch_bounds__(256) void k_final(const int* __restrict__ idxI,
    const long long* __restrict__ qids, const float* __restrict__ colsum,
    const float* __restrict__ scalars, float* __restrict__ out) {
  __shared__ float sbuf[4];
  const int tid = threadIdx.x;
  float ae = 0.f;
  for (int i = tid; i < N_E; i += 256) {
    const float q = colsum[i] * (1.0f / (float)N_TOK);
    ae += q * logf(q + 1e-5f);
  }
  const float aes = blockReduceSum256(ae, sbuf);   // = -avg_entropy
  int cnt = 0;
  for (int p = tid; p < 1024; p += 256) {
    const int v = idxI[p];
    bool eq = true;
    for (int b = 1; b < 16; ++b) eq = eq && (idxI[b * 1024 + p] == v);
    cnt += eq ? 1 : 0;
  }
  const float dc = blockReduceSum256((float)cnt, sbuf);
  if (tid == 0) {
    float denom = 0.f;
    for (int b = 0; b < 16; ++b) denom += (float)(qids[b] + 1ll);
    out[4194304] = scalars[0] / denom;
    out[4194305] = 0.25f * scalars[0] / denom;
    out[4194306] = 0.1f * (scalars[1] * (1.0f / (float)N_TOK) + aes);
    out[4194307] = dc * (1.0f / 1024.0f);
  }
}

extern "C" void kernel_launch(void* const* d_in, const int* in_sizes, int n_in,
                              void* d_out, int out_size, void* d_ws, size_t ws_size,
                              hipStream_t stream) {
  const float*      z    = (const float*)d_in[0];
  const float*      emb  = (const float*)d_in[1];
  const long long*  qids = (const long long*)d_in[2];
  float* out = (float*)d_out;
  float* W   = (float*)d_ws;

  unsigned short* A2 = (unsigned short*)(W + OFF_A2);
  unsigned short* B2 = (unsigned short*)(W + OFF_B2);
  unsigned* rowMaxU = (unsigned*)(W + OFF_RMX);
  float* colsum = W + OFF_CS;
  float* scal   = W + OFF_SC;
  unsigned long long* rowkey = (unsigned long long*)(W + OFF_RK);
  unsigned* ntList = (unsigned*)(W + OFF_NT);
  unsigned* ntc    = (unsigned*)(W + OFF_NTC);
  unsigned* cbc    = (unsigned*)(W + OFF_CBC);
  int* idxI        = (int*)(W + OFF_IDX);
  unsigned long long* cand = (unsigned long long*)(W + OFF_CAND);
  float* zT = (ws_size >= NEED_ZT_BYTES) ? (W + OFF_ZT) : (float*)nullptr;

  k_norm_emb<<<dim3(N_E / 4),     dim3(256), 0, stream>>>(emb, B2, colsum, scal,
                                                          rowkey, ntc, rowMaxU);
  k_norm_z  <<<dim3(256),         dim3(256), 0, stream>>>(z, A2, zT);
  k_pass1   <<<dim3(256, NCH),    dim3(256), 0, stream>>>(A2, B2, cand, cbc, rowMaxU);
  k_cstat2  <<<dim3(256),         dim3(256), 0, stream>>>(cand, cbc, rowMaxU, colsum,
                                                          ntList, ntc, scal);
  k_refine  <<<dim3(1024),        dim3(256), 0, stream>>>(z, zT, emb, ntList, ntc, rowkey);
  k_zq      <<<dim3(256),         dim3(256), 0, stream>>>(A2, B2, rowkey, qids,
                                                          idxI, out + 4194308, out, scal);
  k_final   <<<dim3(1),           dim3(256), 0, stream>>>(idxI, qids, colsum, scal, out);
}

// Round 13
// 549.834 us; speedup vs baseline: 1.2727x; 1.1349x over previous
//
#include <hip/hip_runtime.h>
#include <math.h>

// Problem constants
#define N_TOK   16384
#define N_E     16384
#define CDIM    256
#define NCH     8
#define CHSZ    (N_E / NCH)      // 2048 codes per chunk
#define L2E100  144.26950408889634f   // 100 * log2(e)
#define DELTA_C 0.06f            // candidate window below running row max (t-units)
#define DELTA_D 0.03f            // same window in dot-units (t = 2*dot)
#define EPS_NT  0.008f           // near-tie window for fp64 argmin re-rank
#define CAP_BLK 1536u            // per-block candidate cap (proven r6-r14)
#define NT_CAP  65536u

typedef __attribute__((ext_vector_type(8))) short short8;
typedef __attribute__((ext_vector_type(4))) float f32x4;

// ---- workspace layout (float offsets); base 42.5 MB, zT optional tail ----
#define OFF_A2   0u          // ushort[16384*256] bf16-hi normalized z (token-major)
#define OFF_B2   2097152u    // ushort[16384*256] bf16-hi normalized emb
#define OFF_RMX  4194304u    // 16384 u32 ordered-key row max
#define OFF_CS   4210688u    // 16384 colsum
#define OFF_SC   4227072u    // 16 scalars
#define OFF_RK   4227088u    // 16384 u64 rowkey (8B aligned)
#define OFF_NT   4259856u    // 65536 u32 near-tie list
#define OFF_NTC  4325392u    // 16
#define OFF_CBC  4325408u    // 2048 per-block counts
#define OFF_IDX  4327456u    // 16384 int
#define OFF_CAND 4343840u    // u64[2048*1536] {f32 t | row<<14|col} (8B aligned)
#define OFF_ZT   10635296u   // float[16384*256] raw z token-major (refine coalescing)
#define NEED_ZT_BYTES 59318400ull

__device__ __forceinline__ unsigned short f2bf(float x) {
  unsigned u = __float_as_uint(x);
  unsigned r = (u + 0x7fffu + ((u >> 16) & 1u)) >> 16;
  return (unsigned short)r;
}
__device__ __forceinline__ float bf2f(unsigned short h) {
  return __uint_as_float(((unsigned)h) << 16);
}
__device__ __forceinline__ unsigned fkey(float f) {      // order-preserving float->uint
  unsigned u = __float_as_uint(f);
  return (u & 0x80000000u) ? ~u : (u | 0x80000000u);
}
__device__ __forceinline__ float keyf(unsigned k) {
  return (k & 0x80000000u) ? __uint_as_float(k ^ 0x80000000u) : __uint_as_float(~k);
}

__device__ __forceinline__ void async_load16(const void* g, void* l) {
  __builtin_amdgcn_global_load_lds((const __attribute__((address_space(1))) void*)g,
                                   (__attribute__((address_space(3))) void*)l, 16, 0, 0);
}

__device__ __forceinline__ float blockReduceSum256(float v, float* sbuf) {
  __syncthreads();
  v += __shfl_down(v, 32);
  v += __shfl_down(v, 16);
  v += __shfl_down(v, 8);
  v += __shfl_down(v, 4);
  v += __shfl_down(v, 2);
  v += __shfl_down(v, 1);
  const int tid = threadIdx.x;
  if ((tid & 63) == 0) sbuf[tid >> 6] = v;
  __syncthreads();
  return sbuf[0] + sbuf[1] + sbuf[2] + sbuf[3];
}

// ---------- emb normalize (wave-per-row) + fused workspace zeroing ----------
__global__ __launch_bounds__(256) void k_norm_emb(const float* __restrict__ emb,
    unsigned short* __restrict__ B2, float* __restrict__ colsum,
    float* __restrict__ scalars, unsigned long long* __restrict__ rowkey,
    unsigned* __restrict__ ntc, unsigned* __restrict__ rowMaxU) {
  const int tid = threadIdx.x, lane = tid & 63, wv = tid >> 6;
  if (blockIdx.x < 64) {
    const int i = blockIdx.x * 256 + tid;
    colsum[i] = 0.f;
    rowkey[i] = ~0ull;
    rowMaxU[i] = 0u;
    if (i < 16) { scalars[i] = 0.f; ntc[i] = 0u; }
  }
  const int k = blockIdx.x * 4 + wv;
  const float4 v = *(const float4*)&emb[(size_t)k * CDIM + lane * 4];
  float ss = v.x * v.x + v.y * v.y + v.z * v.z + v.w * v.w;
#pragma unroll
  for (int off = 1; off < 64; off <<= 1) ss += __shfl_xor(ss, off);
  const float r = 1.0f / fmaxf(sqrtf(ss), 1e-12f);
  ushort4 o;
  o.x = f2bf(v.x * r); o.y = f2bf(v.y * r);
  o.z = f2bf(v.z * r); o.w = f2bf(v.w * r);
  *(ushort4*)&B2[(size_t)k * CDIM + lane * 4] = o;
}

// ---------- coalesced z normalize + optional raw token-major copy ----------
__global__ __launch_bounds__(256) void k_norm_z(const float* __restrict__ z,
                                                unsigned short* __restrict__ A2,
                                                float* __restrict__ zT) {
  __shared__ float ssb[4][64];
  __shared__ float rn[64];
  __shared__ unsigned short tile[64 * 264];
  __shared__ float tileF[64 * 260];
  const int b = blockIdx.x >> 4, hw0 = (blockIdx.x & 15) * 64;
  const int tid = threadIdx.x, cg = tid >> 6, hwl = tid & 63;
  float ss = 0.f;
#pragma unroll 8
  for (int i = 0; i < 64; ++i) {
    const int c = cg + i * 4;
    const float x = z[((size_t)(b * CDIM + c) << 10) + hw0 + hwl];
    ss = fmaf(x, x, ss);
  }
  ssb[cg][hwl] = ss;
  __syncthreads();
  if (tid < 64) {
    const float t = ssb[0][tid] + ssb[1][tid] + ssb[2][tid] + ssb[3][tid];
    rn[tid] = 1.0f / fmaxf(sqrtf(t), 1e-12f);
  }
  __syncthreads();
  const float r = rn[hwl];
#pragma unroll 8
  for (int i = 0; i < 64; ++i) {
    const int c = cg + i * 4;
    const float x = z[((size_t)(b * CDIM + c) << 10) + hw0 + hwl];
    tile[hwl * 264 + c] = f2bf(x * r);
    tileF[hwl * 260 + c] = x;
  }
  __syncthreads();
  const int rr = tid >> 5, tt = tid & 31;
#pragma unroll
  for (int it = 0; it < 8; ++it) {
    const int row = rr + 8 * it;
    const int token = b * 1024 + hw0 + row;
    const uint4 v = *(const uint4*)&tile[row * 264 + tt * 8];
    *(uint4*)&A2[(size_t)token * CDIM + tt * 8] = v;
    if (zT != nullptr) {
      const float4 f0 = *(const float4*)&tileF[row * 260 + tt * 4];
      const float4 f1 = *(const float4*)&tileF[row * 260 + 128 + tt * 4];
      *(float4*)&zT[(size_t)token * CDIM + tt * 4] = f0;
      *(float4*)&zT[(size_t)token * CDIM + 128 + tt * 4] = f1;
    }
  }
}

// ============ pass 1 v3c: identical 8 x 32-dim phase structure, 2 x 8 KB dbuf,
// wave-local epilogue; launch_bounds(256,4) -> VGPR cap 128. R10 (cap 85) and
// R12 (cap 102) both spilled (~100-reg unified demand); cap 128 fits with
// headroom. LDS 16.9 KB allows 9 blocks/CU, VGPR allows 4 -> 16 waves/CU
// = 50% occupancy (R7 winner: 42.5% at 33 KB LDS). ============
__global__ __launch_bounds__(256, 4) void k_pass1(const unsigned short* __restrict__ A2,
    const unsigned short* __restrict__ B2,
    unsigned long long* __restrict__ cand, unsigned* __restrict__ cbc,
    unsigned* __restrict__ rowMaxU) {
  __shared__ alignas(16) unsigned short Bt[2][128 * 32];  // 2 x 8 KB B dbuf
  __shared__ unsigned lcnt;
  const int rt = blockIdx.x, chunk = blockIdx.y;   // swizzle: co-resident blocks share chunk
  const int r0 = rt * 64, k0 = chunk * CHSZ;
  const int blin = rt * NCH + chunk;
  const int tid = threadIdx.x, lane = tid & 63, w = tid >> 6;
  const int wr0 = w * 16;                // wave owns rows wr0..wr0+15, cols 0..127
  const int l15 = lane & 15, quad = lane >> 4;

  if (tid == 0) lcnt = 0u;

  // A fragments -> registers: 8 K-slices of 32 dims (same data as R7's afr[st][kk]).
  short8 afr[8];
  {
    const size_t rbase = (size_t)(r0 + wr0 + l15) * CDIM;
#pragma unroll
    for (int j = 0; j < 8; ++j)
      afr[j] = *(const short8*)&A2[rbase + j * 32 + quad * 8];
  }

  // staging: 2 x 16B per thread per phase. lin = i*256+tid -> row=lin>>2,
  // slot=lin&3; LDS[row][slot] holds global dim-group gcg = slot ^ ((row>>1)&3).
  const unsigned short* bsrc[2];
  unsigned bdst[2];
#pragma unroll
  for (int i = 0; i < 2; ++i) {
    const int lin = i * 256 + tid;
    const int row = lin >> 2, slot = lin & 3;
    const int gcg = slot ^ ((row >> 1) & 3);
    bsrc[i] = B2 + (size_t)(k0 + row) * CDIM + gcg * 8;
    bdst[i] = (unsigned)lin * 16u;
  }

  // read offsets: row br (64B stride), slot quad^((br>>1)&3) -> 2-way max aliasing
  int boff[8];
#pragma unroll
  for (int tj = 0; tj < 8; ++tj) {
    const int br = tj * 16 + l15;
    boff[tj] = br * 32 + ((quad ^ ((br >> 1) & 3)) * 8);
  }

  // prologue: stage phase 0 (ct0, st0) into Bt[0]
#pragma unroll
  for (int i = 0; i < 2; ++i)
    async_load16(bsrc[i], (char*)Bt[0] + bdst[i]);
  __syncthreads();

  f32x4 acc[8];
  float runMax[4];
#pragma unroll
  for (int r = 0; r < 4; ++r) runMax[r] = -3.0e38f;

#pragma unroll 1
  for (int ct = 0; ct < 16; ++ct) {
#pragma unroll
    for (int tj = 0; tj < 8; ++tj) acc[tj] = (f32x4){0.f, 0.f, 0.f, 0.f};

#pragma unroll
    for (int st = 0; st < 8; ++st) {
      // prefetch next 32-dim phase into the other buffer
      if (!(ct == 15 && st == 7)) {
        const int noff = (st < 7) ? (ct * 32768 + (st + 1) * 32)
                                  : ((ct + 1) * 32768);
        char* dbuf = (char*)Bt[(st + 1) & 1];
#pragma unroll
        for (int i = 0; i < 2; ++i)
          async_load16(bsrc[i] + noff, dbuf + bdst[i]);
      }
      const unsigned short* bp = Bt[st & 1];
      short8 bfr[8];
#pragma unroll
      for (int tj = 0; tj < 8; ++tj)
        bfr[tj] = *(const short8*)&bp[boff[tj]];
#pragma unroll
      for (int tj = 0; tj < 8; ++tj)
        acc[tj] = __builtin_amdgcn_mfma_f32_16x16x32_bf16(afr[st], bfr[tj],
                                                          acc[tj], 0, 0, 0);

      if (st == 7) {
        // ---- wave-local epilogue (dot-units; t = 2*dot emitted) ----
        const int kb = k0 + ct * 128;
#pragma unroll
        for (int r = 0; r < 4; ++r) {
          float mt = acc[0][r];
#pragma unroll
          for (int tj = 1; tj < 8; ++tj) mt = fmaxf(mt, acc[tj][r]);
          mt = fmaxf(mt, __shfl_xor(mt, 1));
          mt = fmaxf(mt, __shfl_xor(mt, 2));
          mt = fmaxf(mt, __shfl_xor(mt, 4));
          mt = fmaxf(mt, __shfl_xor(mt, 8));
          runMax[r] = fmaxf(runMax[r], mt);
          const float thrD = runMax[r] - DELTA_D;
          const unsigned rowg = (unsigned)(r0 + wr0 + quad * 4 + r);
#pragma unroll
          for (int tj = 0; tj < 8; ++tj) {
            const float d = acc[tj][r];
            if (d >= thrD) {
              const unsigned slot = atomicAdd(&lcnt, 1u);
              if (slot < CAP_BLK) {
                const float t = d + d;
                const unsigned pr = (rowg << 14) | (unsigned)(kb + tj * 16 + l15);
                cand[(size_t)blin * CAP_BLK + slot] =
                    ((unsigned long long)__float_as_uint(t) << 32) | pr;
              }
            }
          }
        }
      }
      __syncthreads();
    }
  }

  // merge per-wave running row maxima to global (t-units = 2*dot)
#pragma unroll
  for (int r = 0; r < 4; ++r)
    if (l15 == 0)
      atomicMax(&rowMaxU[r0 + wr0 + quad * 4 + r], fkey(runMax[r] + runMax[r]));
  if (tid == 0) cbc[blin] = lcnt < CAP_BLK ? lcnt : CAP_BLK;
}

// ---------- fused candidate processing: block = rt, LDS-local Z/E ----------
__global__ __launch_bounds__(256) void k_cstat2(const unsigned long long* __restrict__ cand,
    const unsigned* __restrict__ cbc, const unsigned* __restrict__ rowMaxU,
    float* __restrict__ colsum, unsigned* __restrict__ ntList,
    unsigned* __restrict__ ntc, float* __restrict__ scalars) {
  __shared__ float lM[64], lZ[64], lE[64], lIZ[64];
  __shared__ float sbuf[4];
  const int rt = blockIdx.x, r0 = rt * 64;
  const int tid = threadIdx.x, lane = tid & 63;
  if (tid < 64) {
    lM[tid] = keyf(rowMaxU[r0 + tid]);
    lZ[tid] = 0.f; lE[tid] = 0.f;
  }
  __syncthreads();
  for (int sub = 0; sub < NCH; ++sub) {
    const int blin = rt * NCH + sub;
    const unsigned cnt = cbc[blin] < CAP_BLK ? cbc[blin] : CAP_BLK;
    for (unsigned i = tid; i < cnt; i += 256u) {
      const unsigned long long e = cand[(size_t)blin * CAP_BLK + i];
      const unsigned pr = (unsigned)(e & 0xFFFFFFFu);
      const float t = __uint_as_float((unsigned)(e >> 32));
      const int rowl = (int)((pr >> 14) & 63u);
      const float d = t - lM[rowl];
      const float ex = exp2f(d * L2E100);
      atomicAdd(&lZ[rowl], ex);
      atomicAdd(&lE[rowl], d * 100.0f * ex);
    }
  }
  __syncthreads();
  float ent = 0.f;
  if (tid < 64) {
    const float Z = lZ[tid];
    lIZ[tid] = 1.0f / Z;
    ent = logf(Z) - lE[tid] / Z;
  }
  const float es = blockReduceSum256(ent, sbuf);
  if (tid == 0) atomicAdd(&scalars[1], es);
  __syncthreads();
  for (int sub = 0; sub < NCH; ++sub) {
    const int blin = rt * NCH + sub;
    const unsigned cnt = cbc[blin] < CAP_BLK ? cbc[blin] : CAP_BLK;
    const unsigned lim = (cnt + 255u) & ~255u;
    for (unsigned i = tid; i < lim; i += 256u) {
      bool nt = false;
      unsigned pr = 0u;
      if (i < cnt) {
        const unsigned long long e = cand[(size_t)blin * CAP_BLK + i];
        pr = (unsigned)(e & 0xFFFFFFFu);
        const float t = __uint_as_float((unsigned)(e >> 32));
        const int rowl = (int)((pr >> 14) & 63u);
        const float d = t - lM[rowl];
        atomicAdd(&colsum[pr & 0x3FFFu], exp2f(d * L2E100) * lIZ[rowl]);
        nt = (d >= -EPS_NT);
      }
      const unsigned long long mask = __ballot(nt);
      const unsigned cw = (unsigned)__popcll(mask);
      unsigned base = 0u;
      if (lane == 0 && cw) base = atomicAdd(ntc, cw);
      base = __shfl((int)base, 0);
      if (nt) {
        const unsigned off = (unsigned)__popcll(mask & ((1ull << lane) - 1ull));
        const unsigned s = base + off;
        if (s < NT_CAP) ntList[s] = pr;
      }
    }
  }
}

// ---------- fp64 re-rank of near-tie candidates (coalesced zT if available) ----------
__global__ __launch_bounds__(256) void k_refine(const float* __restrict__ z,
    const float* __restrict__ zT, const float* __restrict__ emb,
    const unsigned* __restrict__ ntList, const unsigned* __restrict__ ntc,
    unsigned long long* __restrict__ rowkey) {
  const unsigned cnt = *ntc;
  const unsigned lim = cnt < NT_CAP ? cnt : NT_CAP;
  const int lane = threadIdx.x & 63, wv = threadIdx.x >> 6;
  for (unsigned slot = blockIdx.x * 4 + wv; slot < lim; slot += gridDim.x * 4) {
    const unsigned pr = ntList[slot];
    const int n = (int)(pr >> 14), k = (int)(pr & 0x3FFFu);
    const int b = n >> 10, hw = n & 1023;
    double sz = 0.0, se = 0.0, sp = 0.0;
#pragma unroll
    for (int u = 0; u < CDIM / 64; ++u) {
      const int c = lane + u * 64;
      const double zv = (zT != nullptr)
          ? (double)zT[(size_t)n * CDIM + c]
          : (double)z[((size_t)(b * CDIM + c) << 10) + hw];
      const double ev = (double)emb[(size_t)k * CDIM + c];
      sz = fma(zv, zv, sz); se = fma(ev, ev, se); sp = fma(zv, ev, sp);
    }
    for (int off = 32; off; off >>= 1) {
      sz += __shfl_down(sz, off);
      se += __shfl_down(se, off);
      sp += __shfl_down(sp, off);
    }
    if (lane == 0) {
      const double nz = fmax(sqrt(sz), 1e-12);
      const double ne = fmax(sqrt(se), 1e-12);
      const double d = sz / (nz * nz) + se / (ne * ne) - 2.0 * sp / (nz * ne);
      const unsigned long long key =
          (((unsigned long long)(d * 140737488355328.0)) << 14) | (unsigned long long)k;
      atomicMin(&rowkey[n], key);
    }
  }
}

// ---------- z_q gather + idx extraction + vq sums ----------
__global__ __launch_bounds__(256) void k_zq(const unsigned short* __restrict__ A2,
    const unsigned short* __restrict__ B2, const unsigned long long* __restrict__ rowkey,
    const long long* __restrict__ qids, int* __restrict__ idxI,
    float* __restrict__ outIdxF, float* __restrict__ outZ,
    float* __restrict__ scalars) {
  __shared__ int lidx[64];
  __shared__ unsigned short tile[64 * 264];
  __shared__ float sbuf[4];
  const int b = blockIdx.x >> 4, hw0 = (blockIdx.x & 15) * 64;
  const int tid = threadIdx.x;
  if (tid < 64) {
    const int n = b * 1024 + hw0 + tid;
    const unsigned long long key = rowkey[n];
    const int k = (key != ~0ull) ? (int)(key & 0x3FFFull) : 0;
    lidx[tid] = k;
    idxI[n] = k;
    outIdxF[n] = (float)k;
  }
  __syncthreads();
  const long long qid = qids[b];
  const int rr = tid >> 5, tt = tid & 31;
  float vq = 0.f;
#pragma unroll
  for (int it = 0; it < 8; ++it) {
    const int row = rr + 8 * it;
    const int token = b * 1024 + hw0 + row;
    union { uint4 v; unsigned short s[8]; } ev, zv;
    ev.v = *(const uint4*)&B2[(size_t)lidx[row] * CDIM + tt * 8];
    zv.v = *(const uint4*)&A2[(size_t)token * CDIM + tt * 8];
    *(uint4*)&tile[row * 264 + tt * 8] = ev.v;
    float dd = 0.f;
#pragma unroll
    for (int u = 0; u < 8; ++u) {
      const float d = bf2f(ev.s[u]) - bf2f(zv.s[u]);
      dd = fmaf(d, d, dd);
    }
    if ((long long)(row & 31) <= qid) vq += dd;
  }
  const float s = blockReduceSum256(vq, sbuf);
  if (tid == 0) atomicAdd(&scalars[0], s * (1.0f / 256.0f));
  __syncthreads();
  const int cg = tid >> 6, hwl = tid & 63;
#pragma unroll 8
  for (int i = 0; i < 64; ++i) {
    const int c = cg + i * 4;
    outZ[((size_t)(b * CDIM + c) << 10) + hw0 + hwl] = bf2f(tile[hwl * 264 + c]);
  }
}

// ---------- final: avg-entropy from colsum + dead-code + scalar outputs ----------
__global__ __launch_bounds__(256) void k_final(const int* __restrict__ idxI,
    const long long* __restrict__ qids, const float* __restrict__ colsum,
    const float* __restrict__ scalars, float* __restrict__ out) {
  __shared__ float sbuf[4];
  const int tid = threadIdx.x;
  float ae = 0.f;
  for (int i = tid; i < N_E; i += 256) {
    const float q = colsum[i] * (1.0f / (float)N_TOK);
    ae += q * logf(q + 1e-5f);
  }
  const float aes = blockReduceSum256(ae, sbuf);   // = -avg_entropy
  int cnt = 0;
  for (int p = tid; p < 1024; p += 256) {
    const int v = idxI[p];
    bool eq = true;
    for (int b = 1; b < 16; ++b) eq = eq && (idxI[b * 1024 + p] == v);
    cnt += eq ? 1 : 0;
  }
  const float dc = blockReduceSum256((float)cnt, sbuf);
  if (tid == 0) {
    float denom = 0.f;
    for (int b = 0; b < 16; ++b) denom += (float)(qids[b] + 1ll);
    out[4194304] = scalars[0] / denom;
    out[4194305] = 0.25f * scalars[0] / denom;
    out[4194306] = 0.1f * (scalars[1] * (1.0f / (float)N_TOK) + aes);
    out[4194307] = dc * (1.0f / 1024.0f);
  }
}

extern "C" void kernel_launch(void* const* d_in, const int* in_sizes, int n_in,
                              void* d_out, int out_size, void* d_ws, size_t ws_size,
                              hipStream_t stream) {
  const float*      z    = (const float*)d_in[0];
  const float*      emb  = (const float*)d_in[1];
  const long long*  qids = (const long long*)d_in[2];
  float* out = (float*)d_out;
  float* W   = (float*)d_ws;

  unsigned short* A2 = (unsigned short*)(W + OFF_A2);
  unsigned short* B2 = (unsigned short*)(W + OFF_B2);
  unsigned* rowMaxU = (unsigned*)(W + OFF_RMX);
  float* colsum = W + OFF_CS;
  float* scal   = W + OFF_SC;
  unsigned long long* rowkey = (unsigned long long*)(W + OFF_RK);
  unsigned* ntList = (unsigned*)(W + OFF_NT);
  unsigned* ntc    = (unsigned*)(W + OFF_NTC);
  unsigned* cbc    = (unsigned*)(W + OFF_CBC);
  int* idxI        = (int*)(W + OFF_IDX);
  unsigned long long* cand = (unsigned long long*)(W + OFF_CAND);
  float* zT = (ws_size >= NEED_ZT_BYTES) ? (W + OFF_ZT) : (float*)nullptr;

  k_norm_emb<<<dim3(N_E / 4),     dim3(256), 0, stream>>>(emb, B2, colsum, scal,
                                                          rowkey, ntc, rowMaxU);
  k_norm_z  <<<dim3(256),         dim3(256), 0, stream>>>(z, A2, zT);
  k_pass1   <<<dim3(256, NCH),    dim3(256), 0, stream>>>(A2, B2, cand, cbc, rowMaxU);
  k_cstat2  <<<dim3(256),         dim3(256), 0, stream>>>(cand, cbc, rowMaxU, colsum,
                                                          ntList, ntc, scal);
  k_refine  <<<dim3(1024),        dim3(256), 0, stream>>>(z, zT, emb, ntList, ntc, rowkey);
  k_zq      <<<dim3(256),         dim3(256), 0, stream>>>(A2, B2, rowkey, qids,
                                                          idxI, out + 4194308, out, scal);
  k_final   <<<dim3(1),           dim3(256), 0, stream>>>(idxI, qids, colsum, scal, out);
}